// Round 3
// baseline (77.957 us; speedup 1.0000x reference)
//
#include <hip/hip_runtime.h>
#include <hip/hip_bf16.h>

#define B_ROWS 8192
#define D_DIM  128
#define CGROUPS 16                  // column groups
#define COLS_PER_GROUP 512
#define ROWS_PER_BLOCK 256          // 8 waves x 32 rows

typedef __attribute__((ext_vector_type(8))) __bf16 bf16x8;
typedef __attribute__((ext_vector_type(4))) float  f32x4;

// ---------------- Kernel 1: l2-normalize rows, cast to bf16 ----------------
__global__ void k_norm(const float* __restrict__ z, __hip_bfloat16* __restrict__ zn) {
    int row  = blockIdx.x * 4 + (threadIdx.x >> 6);
    int lane = threadIdx.x & 63;
    const float2 v = reinterpret_cast<const float2*>(z + (size_t)row * D_DIM)[lane];
    float ss = v.x * v.x + v.y * v.y;
    #pragma unroll
    for (int m = 1; m < 64; m <<= 1) ss += __shfl_xor(ss, m);
    float inv = rsqrtf(fmaxf(ss, 1e-12f));
    __hip_bfloat162 o;
    o.x = __float2bfloat16(v.x * inv);
    o.y = __float2bfloat16(v.y * inv);
    reinterpret_cast<__hip_bfloat162*>(zn + (size_t)row * D_DIM)[lane] = o;
}

// ---------------- Kernel 2: similarity + partial exp-sums ----------------
// Block = 8 waves sharing the SAME B column stream (L1 reuse), each wave owns
// 32 distinct rows (A in registers). Register double-buffered B prefetch.
// s_partial layout: [CGROUPS][B_ROWS]
__global__ __launch_bounds__(512, 4) void k_sim(const __bf16* __restrict__ zn,
                                                float* __restrict__ s_partial,
                                                float* __restrict__ pos) {
    const int w    = threadIdx.x >> 6;
    const int lane = threadIdx.x & 63;
    const int l15  = lane & 15;
    const int lg   = lane >> 4;             // 0..3
    const int rb   = blockIdx.x >> 4;       // 0..31
    const int cg   = blockIdx.x & (CGROUPS - 1);
    const int waveRowBase = rb * ROWS_PER_BLOCK + w * 32;
    const int colStart    = cg * COLS_PER_GROUP;

    // A fragments: 2 strips of 16 rows, 4 k-steps; contiguous 16B per lane
    bf16x8 a[2][4];
    #pragma unroll
    for (int t = 0; t < 2; ++t)
        #pragma unroll
        for (int ks = 0; ks < 4; ++ks)
            a[t][ks] = *reinterpret_cast<const bf16x8*>(
                zn + (waveRowBase + t * 16 + l15) * D_DIM + ks * 32 + lg * 8);

    float s[2][4] = {};

    // exp(sim - 2) = exp2(acc * (2*log2e) + (-2*log2e)), sim = 2*acc (tau=0.5)
    const float C1 = 2.0f * 1.4426950408889634f;
    const float C0 = -2.0f * 1.4426950408889634f;

    auto loadB = [&](bf16x8* b, int col) {
        #pragma unroll
        for (int ks = 0; ks < 4; ++ks)
            b[ks] = *reinterpret_cast<const bf16x8*>(
                zn + (col + l15) * D_DIM + ks * 32 + lg * 8);
    };

    auto compute = [&](const bf16x8* b, int colBase) {
        const bool special = ((unsigned)(colBase - waveRowBase) < 32u);
        const int col = colBase + l15;
        #pragma unroll
        for (int t = 0; t < 2; ++t) {
            f32x4 acc = {0.f, 0.f, 0.f, 0.f};
            #pragma unroll
            for (int ks = 0; ks < 4; ++ks)
                acc = __builtin_amdgcn_mfma_f32_16x16x32_bf16(a[t][ks], b[ks], acc, 0, 0, 0);
            #pragma unroll
            for (int r = 0; r < 4; ++r) {
                float e = exp2f(fmaf(acc[r], C1, C0));
                if (special) {
                    int row = waveRowBase + t * 16 + lg * 4 + r;
                    if (col == row) e = 0.f;                        // mask self
                    if (col == (row ^ 1)) pos[row] = acc[r] * 2.0f; // partner sim
                }
                s[t][r] += e;
            }
        }
    };

    // software pipeline: register double-buffer, prefetch distance 1
    bf16x8 bA[4], bB[4];
    loadB(bA, colStart);
    #pragma unroll 1
    for (int c = colStart; c < colStart + COLS_PER_GROUP; c += 32) {
        loadB(bB, c + 16);
        compute(bA, c);
        loadB(bA, (c + 32) & (B_ROWS - 1));   // wrap: harmless valid prefetch
        compute(bB, c + 16);
    }

    // reduce across the 16 lanes sharing a row (rows are wave-exclusive)
    #pragma unroll
    for (int t = 0; t < 2; ++t)
        #pragma unroll
        for (int r = 0; r < 4; ++r) {
            float v = s[t][r];
            v += __shfl_xor(v, 1);
            v += __shfl_xor(v, 2);
            v += __shfl_xor(v, 4);
            v += __shfl_xor(v, 8);
            if (l15 == 0) {
                int row = waveRowBase + t * 16 + lg * 4 + r;
                s_partial[cg * B_ROWS + row] = v;
            }
        }
}

// ---------------- Kernel 3: per-row loss, per-block partial sums ----------------
__global__ void k_loss_partial(const float* __restrict__ sp, const float* __restrict__ pos,
                               float* __restrict__ part) {
    int i = blockIdx.x * 256 + threadIdx.x;
    float ssum = 0.f;
    #pragma unroll
    for (int c = 0; c < CGROUPS; ++c) ssum += sp[c * B_ROWS + i];
    float v = 2.0f + logf(ssum) - pos[i];
    #pragma unroll
    for (int m = 1; m < 64; m <<= 1) v += __shfl_xor(v, m);
    __shared__ float ls[4];
    if ((threadIdx.x & 63) == 0) ls[threadIdx.x >> 6] = v;
    __syncthreads();
    if (threadIdx.x == 0) part[blockIdx.x] = ls[0] + ls[1] + ls[2] + ls[3];
}

// ---------------- Kernel 4: final reduce ----------------
__global__ void k_final(const float* __restrict__ part, float* __restrict__ out) {
    float v = (threadIdx.x < (B_ROWS / 256)) ? part[threadIdx.x] : 0.f;
    #pragma unroll
    for (int m = 1; m < 64; m <<= 1) v += __shfl_xor(v, m);
    if (threadIdx.x == 0) out[0] = v * (1.0f / (float)B_ROWS);
}

extern "C" void kernel_launch(void* const* d_in, const int* in_sizes, int n_in,
                              void* d_out, int out_size, void* d_ws, size_t ws_size,
                              hipStream_t stream) {
    const float* z = (const float*)d_in[0];
    float* out = (float*)d_out;

    char* ws = (char*)d_ws;
    __hip_bfloat16* zn = (__hip_bfloat16*)ws;                               // 2 MB
    float* s_partial = (float*)(ws + (size_t)B_ROWS * D_DIM * 2);           // 512 KB
    float* pos = (float*)((char*)s_partial + (size_t)CGROUPS * B_ROWS * 4); // 32 KB
    float* part = (float*)((char*)pos + (size_t)B_ROWS * 4);                // 128 B

    // 1) normalize + bf16 cast
    k_norm<<<B_ROWS / 4, 256, 0, stream>>>(z, zn);

    // 2) similarity + partial sums: 32 row-blocks x 16 col-groups, 8 waves/block
    k_sim<<<32 * CGROUPS, 512, 0, stream>>>((const __bf16*)zn, s_partial, pos);

    // 3) per-row loss -> 32 block partials
    k_loss_partial<<<B_ROWS / 256, 256, 0, stream>>>(s_partial, pos, part);

    // 4) final scalar
    k_final<<<1, 64, 0, stream>>>(part, out);
}

// Round 4
// 62.331 us; speedup vs baseline: 1.2507x; 1.2507x over previous
//
#include <hip/hip_runtime.h>
#include <hip/hip_bf16.h>
#include <stdint.h>

#define B_ROWS 8192
#define D_DIM  128
#define TILE   128
#define NT     (B_ROWS / TILE)   // 64 tiles per dimension

typedef __attribute__((ext_vector_type(8))) __bf16 bf16x8;
typedef __attribute__((ext_vector_type(4))) float  f32x4;

typedef __attribute__((address_space(3))) uint32_t lds_u32;
typedef __attribute__((address_space(1))) const uint32_t glb_u32;

__device__ __forceinline__ float fast_exp2(float x) {
    float r;
    asm("v_exp_f32 %0, %1" : "=v"(r) : "v"(x));
    return r;
}

// ---------------- Kernel 1: l2-normalize rows, cast to bf16 ----------------
__global__ void k_norm(const float* __restrict__ z, __hip_bfloat16* __restrict__ zn) {
    int row  = blockIdx.x * 4 + (threadIdx.x >> 6);
    int lane = threadIdx.x & 63;
    const float2 v = reinterpret_cast<const float2*>(z + (size_t)row * D_DIM)[lane];
    float ss = v.x * v.x + v.y * v.y;
    #pragma unroll
    for (int m = 1; m < 64; m <<= 1) ss += __shfl_xor(ss, m);
    float inv = rsqrtf(fmaxf(ss, 1e-12f));
    __hip_bfloat162 o;
    o.x = __float2bfloat16(v.x * inv);
    o.y = __float2bfloat16(v.y * inv);
    reinterpret_cast<__hip_bfloat162*>(zn + (size_t)row * D_DIM)[lane] = o;
}

// ---------------- Kernel 2: 128x128 tile similarity + fused exp epilogue ----
// m97-style: global_load_lds staging (linear LDS dest, inverse-XOR-swizzled
// global source), XOR-swizzled ds_read_b128 fragment reads, single K step.
// Block: 512 thr = 8 waves in 2x4 grid; wave = 64 rows x 32 cols of the tile.
__global__ __launch_bounds__(512, 4) void k_sim(const __bf16* __restrict__ zn,
                                                __hip_bfloat16* __restrict__ s_partial,
                                                float* __restrict__ pos) {
    __shared__ __align__(16) char smem[64 * 1024 + TILE * 4 * sizeof(float)];
    char* sA = smem;
    char* sB = smem + 32 * 1024;
    float (*red)[4] = (float (*)[4])(smem + 64 * 1024);

    const int rt   = blockIdx.x >> 6;   // row tile 0..63
    const int ct   = blockIdx.x & 63;   // col tile 0..63
    const int tid  = threadIdx.x;
    const int lane = tid & 63;
    const int l15  = lane & 15;
    const int lg   = lane >> 4;         // 0..3
    const int w    = tid >> 6;          // 0..7
    const int wr   = w >> 2;            // 0..1 : rows [wr*64, +64)
    const int wc   = w & 3;             // 0..3 : cols [wc*32, +32)

    // ---- stage A (slots 0..2047) and B (2048..4095); 16B per lane per issue.
    // LDS slot s within a tile holds global 16B unit (row = s>>4, u = (s&15)^(row&7))
    // so that ds_read at byte (row*256 + (kb ^ ((row&7)<<4))) returns natural data.
    #pragma unroll
    for (int j = 0; j < 8; ++j) {
        int slot = j * 512 + tid;          // 0..4095, half-uniform per j
        int isB  = slot >> 11;
        int s    = slot & 2047;
        int row  = s >> 4;
        int u    = s & 15;
        int gRow = (isB ? ct : rt) * TILE + row;
        const __bf16* g = zn + (size_t)gRow * D_DIM + ((u ^ (row & 7)) << 3);
        char* l = (isB ? sB : sA) + s * 16;
        __builtin_amdgcn_global_load_lds((glb_u32*)g, (lds_u32*)l, 16, 0, 0);
    }
    __syncthreads();

    // ---- B fragments for this wave's 2 column strips (stay live throughout)
    bf16x8 bfr[2][4];
    #pragma unroll
    for (int cs = 0; cs < 2; ++cs)
        #pragma unroll
        for (int ks = 0; ks < 4; ++ks) {
            int row = wc * 32 + cs * 16 + l15;
            int kb  = ks * 64 + lg * 16;
            bfr[cs][ks] = *reinterpret_cast<const bf16x8*>(
                sB + row * 256 + (kb ^ ((row & 7) << 4)));
        }

    const float C1 = 2.0f * 1.4426950408889634f;   // sim = 2*dot; exp(sim-2)
    const float C0 = -2.0f * 1.4426950408889634f;  //   = exp2(dot*C1 + C0)
    float srow[4][4];   // per (row-strip t, reg r) partial sums over 32 cols
    #pragma unroll
    for (int t = 0; t < 4; ++t)
        #pragma unroll
        for (int r = 0; r < 4; ++r) srow[t][r] = 0.f;

    // ---- compute + fused epilogue, per 16-row strip
    #pragma unroll
    for (int t = 0; t < 4; ++t) {
        bf16x8 afr[4];
        #pragma unroll
        for (int ks = 0; ks < 4; ++ks) {
            int row = wr * 64 + t * 16 + l15;
            int kb  = ks * 64 + lg * 16;
            afr[ks] = *reinterpret_cast<const bf16x8*>(
                sA + row * 256 + (kb ^ ((row & 7) << 4)));
        }
        #pragma unroll
        for (int cs = 0; cs < 2; ++cs) {
            f32x4 acc = {0.f, 0.f, 0.f, 0.f};
            #pragma unroll
            for (int ks = 0; ks < 4; ++ks)
                acc = __builtin_amdgcn_mfma_f32_16x16x32_bf16(afr[ks], bfr[cs][ks], acc, 0, 0, 0);

            const int fragRow = rt * TILE + wr * 64 + t * 16;
            const int fragCol = ct * TILE + wc * 32 + cs * 16;
            if (fragRow == fragCol) {          // diagonal 16x16 frag (wave-uniform)
                const int col = fragCol + l15;
                #pragma unroll
                for (int r = 0; r < 4; ++r) {
                    int row = fragRow + lg * 4 + r;
                    float e = fast_exp2(fmaf(acc[r], C1, C0));
                    if (col == row) e = 0.f;                         // mask self
                    if (col == (row ^ 1)) pos[row] = acc[r] * 2.0f;  // partner sim
                    srow[t][r] += e;
                }
            } else {                            // fast path: no comparisons
                #pragma unroll
                for (int r = 0; r < 4; ++r)
                    srow[t][r] += fast_exp2(fmaf(acc[r], C1, C0));
            }
        }
    }

    // ---- reduce across the 16 lanes sharing a row, cross-wave via LDS
    #pragma unroll
    for (int t = 0; t < 4; ++t)
        #pragma unroll
        for (int r = 0; r < 4; ++r) {
            float v = srow[t][r];
            v += __shfl_xor(v, 1);
            v += __shfl_xor(v, 2);
            v += __shfl_xor(v, 4);
            v += __shfl_xor(v, 8);
            if (l15 == 0) red[wr * 64 + t * 16 + lg * 4 + r][wc] = v;
        }
    __syncthreads();
    if (tid < TILE) {
        float v = red[tid][0] + red[tid][1] + red[tid][2] + red[tid][3];
        s_partial[(size_t)ct * B_ROWS + rt * TILE + tid] = __float2bfloat16(v);
    }
}

// ---------------- Kernel 3: per-row loss, per-block partial sums ------------
__global__ void k_loss_partial(const __hip_bfloat16* __restrict__ sp,
                               const float* __restrict__ pos,
                               float* __restrict__ part) {
    int i = blockIdx.x * 256 + threadIdx.x;
    float ssum = 0.f;
    #pragma unroll
    for (int c = 0; c < NT; ++c) ssum += __bfloat162float(sp[(size_t)c * B_ROWS + i]);
    float v = 2.0f + logf(ssum) - pos[i];
    #pragma unroll
    for (int m = 1; m < 64; m <<= 1) v += __shfl_xor(v, m);
    __shared__ float ls[4];
    if ((threadIdx.x & 63) == 0) ls[threadIdx.x >> 6] = v;
    __syncthreads();
    if (threadIdx.x == 0) part[blockIdx.x] = ls[0] + ls[1] + ls[2] + ls[3];
}

// ---------------- Kernel 4: final reduce ------------------------------------
__global__ void k_final(const float* __restrict__ part, float* __restrict__ out) {
    float v = (threadIdx.x < (B_ROWS / 256)) ? part[threadIdx.x] : 0.f;
    #pragma unroll
    for (int m = 1; m < 64; m <<= 1) v += __shfl_xor(v, m);
    if (threadIdx.x == 0) out[0] = v * (1.0f / (float)B_ROWS);
}

extern "C" void kernel_launch(void* const* d_in, const int* in_sizes, int n_in,
                              void* d_out, int out_size, void* d_ws, size_t ws_size,
                              hipStream_t stream) {
    const float* z = (const float*)d_in[0];
    float* out = (float*)d_out;

    char* ws = (char*)d_ws;
    __hip_bfloat16* zn = (__hip_bfloat16*)ws;                         // 2 MB
    __hip_bfloat16* s_partial = (__hip_bfloat16*)(ws + (size_t)B_ROWS * D_DIM * 2); // 1 MB
    float* pos  = (float*)((char*)s_partial + (size_t)NT * B_ROWS * 2);  // 32 KB
    float* part = (float*)((char*)pos + (size_t)B_ROWS * 4);             // 128 B

    // 1) normalize + bf16 cast
    k_norm<<<B_ROWS / 4, 256, 0, stream>>>(z, zn);

    // 2) 64x64 grid of 128x128 similarity tiles, fused exp + row partials
    k_sim<<<NT * NT, 512, 0, stream>>>((const __bf16*)zn, s_partial, pos);

    // 3) per-row loss -> 32 block partials
    k_loss_partial<<<B_ROWS / 256, 256, 0, stream>>>(s_partial, pos, part);

    // 4) final scalar
    k_final<<<1, 64, 0, stream>>>(part, out);
}

// Round 5
// 37.459 us; speedup vs baseline: 2.0811x; 1.6640x over previous
//
#include <hip/hip_runtime.h>
#include <hip/hip_bf16.h>
#include <stdint.h>

#define B_ROWS 8192
#define D_DIM  128
#define TILE   128
#define NT     64            // tiles per dimension
#define NCR    4             // column ranges (persistent blocks per row-tile)
#define CT_PER_BLK (NT / NCR)  // 16 column tiles per block

typedef __attribute__((ext_vector_type(8))) __bf16 bf16x8;
typedef __attribute__((ext_vector_type(4))) float  f32x4;

typedef __attribute__((address_space(3))) uint32_t lds_u32;
typedef __attribute__((address_space(1))) const uint32_t glb_u32;

__device__ __forceinline__ float fast_exp2(float x) {
    float r;
    asm("v_exp_f32 %0, %1" : "=v"(r) : "v"(x));
    return r;
}

// ---------------- Kernel 1: l2-normalize rows, cast to bf16 ----------------
__global__ void k_norm(const float* __restrict__ z, __hip_bfloat16* __restrict__ zn) {
    int row  = blockIdx.x * 4 + (threadIdx.x >> 6);
    int lane = threadIdx.x & 63;
    const float2 v = reinterpret_cast<const float2*>(z + (size_t)row * D_DIM)[lane];
    float ss = v.x * v.x + v.y * v.y;
    #pragma unroll
    for (int m = 1; m < 64; m <<= 1) ss += __shfl_xor(ss, m);
    float inv = rsqrtf(fmaxf(ss, 1e-12f));
    __hip_bfloat162 o;
    o.x = __float2bfloat16(v.x * inv);
    o.y = __float2bfloat16(v.y * inv);
    reinterpret_cast<__hip_bfloat162*>(zn + (size_t)row * D_DIM)[lane] = o;
}

// ---------------- Kernel 2: persistent-tile similarity + fused exp ----------
// 256 blocks (1/CU). Block = (rt, 16 cts). A staged once -> registers.
// B double-buffered in LDS, prefetch distance 1 (T3 minimum 2-phase).
// Swizzle scheme identical to R4 (validated): linear LDS dest for
// global_load_lds, inverse-XOR global source, XOR-swizzled ds_read_b128.
__global__ __launch_bounds__(512, 2) void k_sim(const __bf16* __restrict__ zn,
                                                float* __restrict__ s_partial,
                                                float* __restrict__ pos) {
    __shared__ __align__(16) char smem[32 * 1024 * 3 + TILE * 4 * sizeof(float)];
    char* sA = smem;                   // 32 KB
    char* sB = smem + 32768;           // 2 x 32 KB double buffer
    float (*red)[4] = (float (*)[4])(smem + 98304);

    const int tid  = threadIdx.x;
    const int lane = tid & 63;
    const int l15  = lane & 15;
    const int lg   = lane >> 4;        // 0..3
    const int w    = tid >> 6;         // 0..7
    const int wr   = w >> 2;           // 0..1 : rows [wr*64, +64)
    const int wc   = w & 3;            // 0..3 : cols [wc*32, +32)
    const int rt   = blockIdx.x >> 2;  // 0..63
    const int cr   = blockIdx.x & 3;   // 0..3
    const int ct0  = cr * CT_PER_BLK;

    // stage a 128-row tile (32 KB): 4 slots of 16B per thread, linear LDS dest,
    // inverse-swizzled global source (involution u ^= row&7 on 16B units)
    auto stage = [&](int gRowBase, char* dst) {
        #pragma unroll
        for (int j = 0; j < 4; ++j) {
            int slot = j * 512 + tid;
            int row  = slot >> 4;
            int u    = slot & 15;
            const __bf16* g = zn + (size_t)(gRowBase + row) * D_DIM + ((u ^ (row & 7)) << 3);
            __builtin_amdgcn_global_load_lds((glb_u32*)g, (lds_u32*)(dst + slot * 16), 16, 0, 0);
        }
    };

    stage(rt * TILE, sA);
    stage(ct0 * TILE, sB);             // buffer 0
    asm volatile("s_waitcnt vmcnt(0)");
    __syncthreads();

    // A fragments -> registers, held for the whole kernel (64 VGPRs)
    bf16x8 afr[4][4];
    #pragma unroll
    for (int t = 0; t < 4; ++t)
        #pragma unroll
        for (int ks = 0; ks < 4; ++ks) {
            int row = wr * 64 + t * 16 + l15;
            int kb  = ks * 64 + lg * 16;
            afr[t][ks] = *reinterpret_cast<const bf16x8*>(
                sA + row * 256 + (kb ^ ((row & 7) << 4)));
        }

    const float C1 = 2.0f * 1.4426950408889634f;   // sim = 2*dot (tau = 0.5)
    const float C0 = -2.0f * 1.4426950408889634f;  // exp(sim-2) = exp2(dot*C1 + C0)
    float srow[4][4];
    #pragma unroll
    for (int t = 0; t < 4; ++t)
        #pragma unroll
        for (int r = 0; r < 4; ++r) srow[t][r] = 0.f;

    int bufOff = 0;
    #pragma unroll 1
    for (int i = 0; i < CT_PER_BLK; ++i) {
        const int ct = ct0 + i;
        if (i + 1 < CT_PER_BLK)
            stage((ct + 1) * TILE, sB + (bufOff ^ 32768));   // prefetch next B

        const char* bb = sB + bufOff;
        bf16x8 bfr[2][4];
        #pragma unroll
        for (int cs = 0; cs < 2; ++cs)
            #pragma unroll
            for (int ks = 0; ks < 4; ++ks) {
                int row = wc * 32 + cs * 16 + l15;
                int kb  = ks * 64 + lg * 16;
                bfr[cs][ks] = *reinterpret_cast<const bf16x8*>(
                    bb + row * 256 + (kb ^ ((row & 7) << 4)));
            }

        const bool diagTile = (ct == rt);
        #pragma unroll
        for (int t = 0; t < 4; ++t) {
            #pragma unroll
            for (int cs = 0; cs < 2; ++cs) {
                f32x4 acc = {0.f, 0.f, 0.f, 0.f};
                #pragma unroll
                for (int ks = 0; ks < 4; ++ks)
                    acc = __builtin_amdgcn_mfma_f32_16x16x32_bf16(afr[t][ks], bfr[cs][ks], acc, 0, 0, 0);

                if (diagTile && (wr * 64 + t * 16 == wc * 32 + cs * 16)) {
                    // diagonal 16x16 fragment (wave-uniform condition)
                    const int fragBase = rt * TILE + wr * 64 + t * 16;
                    const int col = fragBase + l15;
                    #pragma unroll
                    for (int r = 0; r < 4; ++r) {
                        int row = fragBase + lg * 4 + r;
                        float e = fast_exp2(fmaf(acc[r], C1, C0));
                        if (col == row) e = 0.f;                         // mask self
                        if (col == (row ^ 1)) pos[row] = acc[r] * 2.0f;  // partner sim
                        srow[t][r] += e;
                    }
                } else {
                    #pragma unroll
                    for (int r = 0; r < 4; ++r)
                        srow[t][r] += fast_exp2(fmaf(acc[r], C1, C0));
                }
            }
        }
        __syncthreads();   // drains vmcnt+lgkmcnt: prefetched buffer ready, cur reusable
        bufOff ^= 32768;
    }

    // final reduction: 16 lanes sharing a row -> cross-wave (wc) via LDS
    #pragma unroll
    for (int t = 0; t < 4; ++t)
        #pragma unroll
        for (int r = 0; r < 4; ++r) {
            float v = srow[t][r];
            v += __shfl_xor(v, 1);
            v += __shfl_xor(v, 2);
            v += __shfl_xor(v, 4);
            v += __shfl_xor(v, 8);
            if (l15 == 0) red[wr * 64 + t * 16 + lg * 4 + r][wc] = v;
        }
    __syncthreads();
    if (tid < TILE) {
        float v = red[tid][0] + red[tid][1] + red[tid][2] + red[tid][3];
        s_partial[(size_t)cr * B_ROWS + rt * TILE + tid] = v;
    }
}

// ---------------- Kernel 3: per-row loss, per-block partial sums ------------
__global__ void k_loss_partial(const float* __restrict__ sp,
                               const float* __restrict__ pos,
                               float* __restrict__ part) {
    int i = blockIdx.x * 256 + threadIdx.x;
    float ssum = sp[i] + sp[B_ROWS + i] + sp[2 * B_ROWS + i] + sp[3 * B_ROWS + i];
    float v = 2.0f + logf(ssum) - pos[i];
    #pragma unroll
    for (int m = 1; m < 64; m <<= 1) v += __shfl_xor(v, m);
    __shared__ float ls[4];
    if ((threadIdx.x & 63) == 0) ls[threadIdx.x >> 6] = v;
    __syncthreads();
    if (threadIdx.x == 0) part[blockIdx.x] = ls[0] + ls[1] + ls[2] + ls[3];
}

// ---------------- Kernel 4: final reduce ------------------------------------
__global__ void k_final(const float* __restrict__ part, float* __restrict__ out) {
    float v = (threadIdx.x < (B_ROWS / 256)) ? part[threadIdx.x] : 0.f;
    #pragma unroll
    for (int m = 1; m < 64; m <<= 1) v += __shfl_xor(v, m);
    if (threadIdx.x == 0) out[0] = v * (1.0f / (float)B_ROWS);
}

extern "C" void kernel_launch(void* const* d_in, const int* in_sizes, int n_in,
                              void* d_out, int out_size, void* d_ws, size_t ws_size,
                              hipStream_t stream) {
    const float* z = (const float*)d_in[0];
    float* out = (float*)d_out;

    char* ws = (char*)d_ws;
    __hip_bfloat16* zn = (__hip_bfloat16*)ws;                          // 2 MB
    float* s_partial = (float*)(ws + (size_t)B_ROWS * D_DIM * 2);      // 128 KB
    float* pos  = (float*)((char*)s_partial + (size_t)NCR * B_ROWS * 4); // 32 KB
    float* part = (float*)((char*)pos + (size_t)B_ROWS * 4);           // 128 B

    // 1) normalize + bf16 cast
    k_norm<<<B_ROWS / 4, 256, 0, stream>>>(z, zn);

    // 2) persistent similarity: 64 row-tiles x 4 col-ranges = 256 blocks (1/CU)
    k_sim<<<NT * NCR, 512, 0, stream>>>((const __bf16*)zn, s_partial, pos);

    // 3) per-row loss -> 32 block partials
    k_loss_partial<<<B_ROWS / 256, 256, 0, stream>>>(s_partial, pos, part);

    // 4) final scalar
    k_final<<<1, 64, 0, stream>>>(part, out);
}